// Round 3
// baseline (578.466 us; speedup 1.0000x reference)
//
#include <hip/hip_runtime.h>
#include <hip/hip_bf16.h>

typedef __bf16 bf16;
typedef bf16 bf16x8 __attribute__((ext_vector_type(8)));
typedef float f32x4 __attribute__((ext_vector_type(4)));
typedef unsigned short u16;

#define B_ 4
#define S_ 2048
#define D_ 1024
#define H_ 16
#define HD_ 64

#define NEG_SENT -30000.0f

// workspace layout (bf16 element offsets)
#define XN_OFF   ((size_t)0)          // 8388608 elems; reused as Ab after QKV
#define WT_OFF   ((size_t)8388608)    // 4 x 1048576
#define BN_OFF   ((size_t)12582912)   // 4 x 1024
#define FLAG_BYTE ((size_t)25174016)  // int flag
#define Q_OFF    ((size_t)12587520)
#define K_OFF    ((size_t)20976128)
#define VT_OFF   ((size_t)29364736)

union Pack4 { bf16 b[4]; uint2 q; };

__device__ __forceinline__ float expe(float x) {
    // e^x with clamped argument: sentinels give ~2^-115, never inf/NaN.
    return exp2f(fmaxf(x, -80.0f) * 1.4426950408889634f);
}

__device__ __forceinline__ void load16(const bf16* g, bf16* l) {
    __builtin_amdgcn_global_load_lds(
        (const __attribute__((address_space(1))) void*)g,
        (__attribute__((address_space(3))) void*)l, 16, 0, 0);
}

// ---------------- dtype detection ----------------
// fp32 buffer: even 16-bit words are mantissa noise (~14% sane exponent).
// bf16 buffer: every word is a bf16 N(0,1) value (~100% sane exponent).
__global__ __launch_bounds__(256) void detect_k(const u16* __restrict__ x,
                                                int* __restrict__ flag)
{
    __shared__ int cnt;
    if (threadIdx.x == 0) cnt = 0;
    __syncthreads();
    int c = 0;
    for (int i = threadIdx.x; i < 4096; i += 256) {
        u16 w = x[i * 2];            // even-indexed words
        int e = (w >> 7) & 0xFF;
        if (e >= 100 && e <= 135) c++;
    }
    atomicAdd(&cnt, c);
    __syncthreads();
    if (threadIdx.x == 0) *flag = (cnt > 2048) ? 1 : 0;   // 1 = bf16
}

// ---------------- input normalization: x -> bf16 XN ----------------
__global__ __launch_bounds__(256) void norm_x_k(const void* __restrict__ src,
                                                bf16* __restrict__ dst,
                                                const int* __restrict__ flag)
{
    const int qi = blockIdx.x * 256 + threadIdx.x;   // quad index, 4 elems each
    if (*flag) {
        ((uint2*)dst)[qi] = ((const uint2*)src)[qi];
    } else {
        float4 v = ((const float4*)src)[qi];
        Pack4 p;
        p.b[0] = (bf16)v.x; p.b[1] = (bf16)v.y;
        p.b[2] = (bf16)v.z; p.b[3] = (bf16)v.w;
        ((uint2*)dst)[qi] = p.q;
    }
}

// ---------------- bias normalization ----------------
__global__ __launch_bounds__(256) void norm_b_k(
    const void* __restrict__ b0, const void* __restrict__ b1,
    const void* __restrict__ b2, const void* __restrict__ b3,
    bf16* __restrict__ BN, const int* __restrict__ flag)
{
    const int mat = blockIdx.x;
    const void* src = (mat == 0) ? b0 : (mat == 1) ? b1 : (mat == 2) ? b2 : b3;
    bf16* dst = BN + mat * 1024;
    const int i = threadIdx.x * 4;
    if (*flag) {
        ((uint2*)(dst + i))[0] = *(const uint2*)((const bf16*)src + i);
    } else {
        const float* s = (const float*)src;
        Pack4 p;
        p.b[0] = (bf16)s[i + 0]; p.b[1] = (bf16)s[i + 1];
        p.b[2] = (bf16)s[i + 2]; p.b[3] = (bf16)s[i + 3];
        ((uint2*)(dst + i))[0] = p.q;
    }
}

// ---------- weight normalize + transpose: W[K][N] -> WT[N][K] (bf16) ----------
__global__ __launch_bounds__(256) void transpose_w(
    const void* __restrict__ W0, const void* __restrict__ W1,
    const void* __restrict__ W2, const void* __restrict__ W3,
    bf16* __restrict__ WT, const int* __restrict__ flag)
{
    __shared__ __align__(16) bf16 tile[64][65];
    const int mat = blockIdx.z;
    const void* W = (mat == 0) ? W0 : (mat == 1) ? W1 : (mat == 2) ? W2 : W3;
    bf16* O = WT + ((size_t)mat << 20);
    const int r0 = blockIdx.y * 64, c0 = blockIdx.x * 64;
    const int t = threadIdx.x;
    const int isb = *flag;
    #pragma unroll
    for (int i = 0; i < 16; ++i) {
        int idx = t + i * 256;
        int r = idx >> 6, c = idx & 63;
        size_t off = (size_t)(r0 + r) * D_ + c0 + c;
        tile[r][c] = isb ? ((const bf16*)W)[off] : (bf16)((const float*)W)[off];
    }
    __syncthreads();
    #pragma unroll
    for (int i = 0; i < 16; ++i) {
        int idx = t + i * 256;
        int rr = idx & 63, cc = idx >> 6;
        O[(size_t)(c0 + cc) * D_ + r0 + rr] = tile[rr][cc];
    }
}

// ---------------- shared 128x128 GEMM mainloop (m97 structure) ----------------
__device__ __forceinline__ void gemm_core(const bf16* __restrict__ A,
                                          const bf16* __restrict__ Bt,
                                          bf16* lA, bf16* lB,
                                          f32x4 acc[4][4], int m0, int n0)
{
    const int t = threadIdx.x;
    const int lane = t & 63;
    const int wave = t >> 6;
    const int wm = (wave >> 1) << 6;
    const int wn = (wave & 1) << 6;
    const int quad = lane >> 4;
    const int col = lane & 15;
    for (int k0 = 0; k0 < D_; k0 += 32) {
        #pragma unroll
        for (int i = 0; i < 2; ++i) {
            int slot = t + i * 256;
            int row = slot >> 2;
            int kc = (slot & 3) << 3;
            load16(A + (size_t)(m0 + row) * D_ + k0 + kc, lA + slot * 8);
            load16(Bt + (size_t)(n0 + row) * D_ + k0 + kc, lB + slot * 8);
        }
        __syncthreads();
        bf16x8 af[4], bfr[4];
        #pragma unroll
        for (int mi = 0; mi < 4; ++mi)
            af[mi] = *(const bf16x8*)(lA + (wm + mi * 16 + col) * 32 + quad * 8);
        #pragma unroll
        for (int ni = 0; ni < 4; ++ni)
            bfr[ni] = *(const bf16x8*)(lB + (wn + ni * 16 + col) * 32 + quad * 8);
        #pragma unroll
        for (int mi = 0; mi < 4; ++mi)
            #pragma unroll
            for (int ni = 0; ni < 4; ++ni)
                acc[mi][ni] = __builtin_amdgcn_mfma_f32_16x16x32_bf16(
                    af[mi], bfr[ni], acc[mi][ni], 0, 0, 0);
        __syncthreads();
    }
}

// ---------------- QKV projection ----------------
__global__ __launch_bounds__(256) void gemm_qkv_k(
    const bf16* __restrict__ X, const bf16* __restrict__ WT,
    const bf16* __restrict__ BN,
    bf16* __restrict__ Qo, bf16* __restrict__ Ko, bf16* __restrict__ Vo)
{
    __shared__ __align__(16) bf16 lA[128 * 32];
    __shared__ __align__(16) bf16 lB[128 * 32];
    const int mode = blockIdx.z;
    const bf16* Wsel = WT + ((size_t)mode << 20);
    const bf16* bias = BN + mode * 1024;
    f32x4 acc[4][4];
    const f32x4 z = {0.f, 0.f, 0.f, 0.f};
    #pragma unroll
    for (int i = 0; i < 4; ++i)
        #pragma unroll
        for (int j = 0; j < 4; ++j) acc[i][j] = z;
    const int m0 = blockIdx.x * 128, n0 = blockIdx.y * 128;
    gemm_core(X, Wsel, lA, lB, acc, m0, n0);
    const int t = threadIdx.x, lane = t & 63, wave = t >> 6;
    const int wm = (wave >> 1) << 6, wn = (wave & 1) << 6;
    const int quad = lane >> 4, col = lane & 15;
    const float scale = (mode == 0) ? 0.125f : 1.0f;
    #pragma unroll
    for (int mi = 0; mi < 4; ++mi) {
        int gm = m0 + wm + mi * 16 + quad * 4;
        int b = gm >> 11, srow = gm & 2047;
        #pragma unroll
        for (int ni = 0; ni < 4; ++ni) {
            int gn = n0 + wn + ni * 16 + col;
            float bb = (float)bias[gn];
            int h = gn >> 6, hd = gn & 63;
            #pragma unroll
            for (int r = 0; r < 4; ++r) {
                float v = (acc[mi][ni][r] + bb) * scale;
                if (mode == 2)
                    Vo[(((size_t)b * H_ + h) * HD_ + hd) * S_ + srow + r] = (bf16)v;
                else if (mode == 1)
                    Ko[(((size_t)b * H_ + h) * S_ + srow + r) * HD_ + hd] = (bf16)v;
                else
                    Qo[(((size_t)b * H_ + h) * S_ + srow + r) * HD_ + hd] = (bf16)v;
            }
        }
    }
}

// ---------------- flash attention (causal) ----------------
__global__ __launch_bounds__(256) void attn_k(
    const bf16* __restrict__ Q, const bf16* __restrict__ K,
    const bf16* __restrict__ VT, bf16* __restrict__ Aout)
{
    __shared__ __align__(16) bf16 lK[32 * 64];   // [k][d]
    __shared__ __align__(16) bf16 lV[64 * 32];   // [d][k]
    __shared__ __align__(16) bf16 lP[4][32 * 32];// per-wave [q][k]
    const int bh = blockIdx.y;
    const int qc = (int)gridDim.x - 1 - (int)blockIdx.x;
    const int q0 = qc * 128;
    const bf16* Qp = Q + (size_t)bh * S_ * HD_;
    const bf16* Kp = K + (size_t)bh * S_ * HD_;
    const bf16* Vp = VT + (size_t)bh * HD_ * S_;
    const int t = threadIdx.x, lane = t & 63, w = t >> 6;
    const int quad = lane >> 4, col = lane & 15;
    const int wq0 = q0 + w * 32;

    bf16x8 qf[2][2];
    #pragma unroll
    for (int mi = 0; mi < 2; ++mi)
        #pragma unroll
        for (int cc = 0; cc < 2; ++cc)
            qf[mi][cc] = *(const bf16x8*)(Qp + (size_t)(wq0 + mi * 16 + col) * HD_
                                          + cc * 32 + quad * 8);
    f32x4 o[2][4];
    float mst[2][4], lst[2][4];
    const f32x4 z = {0.f, 0.f, 0.f, 0.f};
    #pragma unroll
    for (int mi = 0; mi < 2; ++mi) {
        #pragma unroll
        for (int dn = 0; dn < 4; ++dn) o[mi][dn] = z;
        #pragma unroll
        for (int r = 0; r < 4; ++r) { mst[mi][r] = NEG_SENT; lst[mi][r] = 0.f; }
    }

    const int kend = q0 + 128;
    for (int k0 = 0; k0 < kend; k0 += 32) {
        {
            int krow = t >> 3, dc = (t & 7) << 3;
            load16(Kp + (size_t)(k0 + krow) * HD_ + dc, lK + t * 8);
            int vrow = t >> 2, kc2 = (t & 3) << 3;
            load16(Vp + (size_t)vrow * S_ + k0 + kc2, lV + t * 8);
        }
        __syncthreads();
        if (k0 < wq0 + 32) {
            bf16x8 kf[2][2];
            #pragma unroll
            for (int ni = 0; ni < 2; ++ni)
                #pragma unroll
                for (int cc = 0; cc < 2; ++cc)
                    kf[ni][cc] = *(const bf16x8*)(lK + (ni * 16 + col) * 64
                                                  + cc * 32 + quad * 8);
            f32x4 sc[2][2];
            #pragma unroll
            for (int mi = 0; mi < 2; ++mi)
                #pragma unroll
                for (int ni = 0; ni < 2; ++ni) sc[mi][ni] = z;
            #pragma unroll
            for (int cc = 0; cc < 2; ++cc)
                #pragma unroll
                for (int mi = 0; mi < 2; ++mi)
                    #pragma unroll
                    for (int ni = 0; ni < 2; ++ni)
                        sc[mi][ni] = __builtin_amdgcn_mfma_f32_16x16x32_bf16(
                            qf[mi][cc], kf[ni][cc], sc[mi][ni], 0, 0, 0);
            if (k0 == wq0) {
                #pragma unroll
                for (int mi = 0; mi < 2; ++mi)
                    #pragma unroll
                    for (int ni = 0; ni < 2; ++ni)
                        #pragma unroll
                        for (int r = 0; r < 4; ++r)
                            if (ni * 16 + col > mi * 16 + quad * 4 + r)
                                sc[mi][ni][r] = NEG_SENT;
            }
            #pragma unroll
            for (int mi = 0; mi < 2; ++mi) {
                float mn[4], al[4];
                #pragma unroll
                for (int r = 0; r < 4; ++r) {
                    float v = fmaxf(sc[mi][0][r], sc[mi][1][r]);
                    v = fmaxf(v, __shfl_xor(v, 1));
                    v = fmaxf(v, __shfl_xor(v, 2));
                    v = fmaxf(v, __shfl_xor(v, 4));
                    v = fmaxf(v, __shfl_xor(v, 8));
                    mn[r] = fmaxf(mst[mi][r], v);
                    al[r] = expe(mst[mi][r] - mn[r]);
                    mst[mi][r] = mn[r];
                }
                #pragma unroll
                for (int ni = 0; ni < 2; ++ni)
                    #pragma unroll
                    for (int r = 0; r < 4; ++r)
                        sc[mi][ni][r] = expe(sc[mi][ni][r] - mn[r]);
                #pragma unroll
                for (int r = 0; r < 4; ++r) {
                    float sv = sc[mi][0][r] + sc[mi][1][r];
                    sv += __shfl_xor(sv, 1);
                    sv += __shfl_xor(sv, 2);
                    sv += __shfl_xor(sv, 4);
                    sv += __shfl_xor(sv, 8);
                    lst[mi][r] = lst[mi][r] * al[r] + sv;
                }
                #pragma unroll
                for (int dn = 0; dn < 4; ++dn)
                    #pragma unroll
                    for (int r = 0; r < 4; ++r) o[mi][dn][r] *= al[r];
                #pragma unroll
                for (int ni = 0; ni < 2; ++ni)
                    #pragma unroll
                    for (int r = 0; r < 4; ++r)
                        lP[w][(mi * 16 + quad * 4 + r) * 32 + ni * 16 + col] =
                            (bf16)sc[mi][ni][r];
            }
            asm volatile("s_waitcnt lgkmcnt(0)" ::: "memory");
            bf16x8 pf[2], vf[4];
            #pragma unroll
            for (int mi = 0; mi < 2; ++mi)
                pf[mi] = *(const bf16x8*)(&lP[w][(mi * 16 + col) * 32 + quad * 8]);
            #pragma unroll
            for (int dn = 0; dn < 4; ++dn)
                vf[dn] = *(const bf16x8*)(lV + (dn * 16 + col) * 32 + quad * 8);
            #pragma unroll
            for (int mi = 0; mi < 2; ++mi)
                #pragma unroll
                for (int dn = 0; dn < 4; ++dn)
                    o[mi][dn] = __builtin_amdgcn_mfma_f32_16x16x32_bf16(
                        pf[mi], vf[dn], o[mi][dn], 0, 0, 0);
        }
        __syncthreads();
    }
    const int b = bh >> 4, h = bh & 15;
    #pragma unroll
    for (int mi = 0; mi < 2; ++mi)
        #pragma unroll
        for (int r = 0; r < 4; ++r) {
            float inv = 1.f / fmaxf(lst[mi][r], 1e-30f);
            int srow = wq0 + mi * 16 + quad * 4 + r;
            #pragma unroll
            for (int dn = 0; dn < 4; ++dn)
                Aout[((size_t)b * S_ + srow) * D_ + h * HD_ + dn * 16 + col] =
                    (bf16)(o[mi][dn][r] * inv);
        }
}

// ---------------- output projection (dtype-aware store) ----------------
__global__ __launch_bounds__(256) void gemm_out_k(
    const bf16* __restrict__ A, const bf16* __restrict__ WoT,
    const bf16* __restrict__ Bo, void* __restrict__ Out,
    const int* __restrict__ flag)
{
    __shared__ __align__(16) bf16 lA[128 * 32];
    __shared__ __align__(16) bf16 lB[128 * 32];
    f32x4 acc[4][4];
    const f32x4 z = {0.f, 0.f, 0.f, 0.f};
    #pragma unroll
    for (int i = 0; i < 4; ++i)
        #pragma unroll
        for (int j = 0; j < 4; ++j) acc[i][j] = z;
    const int m0 = blockIdx.x * 128, n0 = blockIdx.y * 128;
    gemm_core(A, WoT, lA, lB, acc, m0, n0);
    const int t = threadIdx.x, lane = t & 63, wave = t >> 6;
    const int wm = (wave >> 1) << 6, wn = (wave & 1) << 6;
    const int quad = lane >> 4, col = lane & 15;
    const int isb = *flag;
    #pragma unroll
    for (int mi = 0; mi < 4; ++mi) {
        int gm = m0 + wm + mi * 16 + quad * 4;
        #pragma unroll
        for (int ni = 0; ni < 4; ++ni) {
            int gn = n0 + wn + ni * 16 + col;
            float bb = (float)Bo[gn];
            #pragma unroll
            for (int r = 0; r < 4; ++r) {
                float v = acc[mi][ni][r] + bb;
                size_t off = (size_t)(gm + r) * D_ + gn;
                if (isb) ((bf16*)Out)[off] = (bf16)v;
                else     ((float*)Out)[off] = v;
            }
        }
    }
}

extern "C" void kernel_launch(void* const* d_in, const int* in_sizes, int n_in,
                              void* d_out, int out_size, void* d_ws, size_t ws_size,
                              hipStream_t stream)
{
    const void* x  = d_in[0];
    const void* wq = d_in[1];
    const void* bq = d_in[2];
    const void* wk = d_in[3];
    const void* bk = d_in[4];
    const void* wv = d_in[5];
    const void* bv = d_in[6];
    const void* wo = d_in[7];
    const void* bo = d_in[8];

    bf16* ws  = (bf16*)d_ws;
    bf16* XN  = ws + XN_OFF;                 // also reused as Ab
    bf16* WT  = ws + WT_OFF;
    bf16* BN  = ws + BN_OFF;
    int*  flag = (int*)((char*)d_ws + FLAG_BYTE);
    bf16* Qb  = ws + Q_OFF;
    bf16* Kb  = ws + K_OFF;
    bf16* VTb = ws + VT_OFF;
    bf16* Ab  = XN;

    hipLaunchKernelGGL(detect_k, dim3(1), dim3(256), 0, stream,
                       (const u16*)x, flag);
    hipLaunchKernelGGL(norm_x_k, dim3(8192), dim3(256), 0, stream,
                       x, XN, flag);
    hipLaunchKernelGGL(transpose_w, dim3(16, 16, 4), dim3(256), 0, stream,
                       wq, wk, wv, wo, WT, flag);
    hipLaunchKernelGGL(norm_b_k, dim3(4), dim3(256), 0, stream,
                       bq, bk, bv, bo, BN, flag);
    hipLaunchKernelGGL(gemm_qkv_k, dim3(64, 8, 3), dim3(256), 0, stream,
                       XN, WT, BN, Qb, Kb, VTb);
    hipLaunchKernelGGL(attn_k, dim3(16, 64), dim3(256), 0, stream,
                       Qb, Kb, VTb, Ab);
    hipLaunchKernelGGL(gemm_out_k, dim3(64, 8), dim3(256), 0, stream,
                       Ab, WT + ((size_t)3u << 20), BN + 3072, d_out, flag);
}

// Round 4
// 394.884 us; speedup vs baseline: 1.4649x; 1.4649x over previous
//
#include <hip/hip_runtime.h>
#include <hip/hip_bf16.h>

typedef __bf16 bf16;
typedef bf16 bf16x8 __attribute__((ext_vector_type(8)));
typedef float f32x4 __attribute__((ext_vector_type(4)));
typedef unsigned short u16;

#define B_ 4
#define S_ 2048
#define D_ 1024
#define H_ 16
#define HD_ 64

#define NEG_SENT -30000.0f

// workspace layout (bf16 element offsets)
#define XN_OFF   ((size_t)0)          // 8388608 elems; reused as Ab after QKV
#define WT_OFF   ((size_t)8388608)    // 4 x 1048576
#define BN_OFF   ((size_t)12582912)   // 4 x 1024
#define FLAG_BYTE ((size_t)25174016)  // int flag
#define Q_OFF    ((size_t)12587520)
#define K_OFF    ((size_t)20976128)
#define VT_OFF   ((size_t)29364736)

union Pack4 { bf16 b[4]; uint2 q; };

__device__ __forceinline__ void load16(const bf16* g, bf16* l) {
    __builtin_amdgcn_global_load_lds(
        (const __attribute__((address_space(1))) void*)g,
        (__attribute__((address_space(3))) void*)l, 16, 0, 0);
}

// ---------------- dtype detection ----------------
__global__ __launch_bounds__(256) void detect_k(const u16* __restrict__ x,
                                                int* __restrict__ flag)
{
    __shared__ int cnt;
    if (threadIdx.x == 0) cnt = 0;
    __syncthreads();
    int c = 0;
    for (int i = threadIdx.x; i < 4096; i += 256) {
        u16 w = x[i * 2];            // even-indexed words
        int e = (w >> 7) & 0xFF;
        if (e >= 100 && e <= 135) c++;
    }
    atomicAdd(&cnt, c);
    __syncthreads();
    if (threadIdx.x == 0) *flag = (cnt > 2048) ? 1 : 0;   // 1 = bf16
}

// ---------------- input normalization: x -> bf16 XN ----------------
__global__ __launch_bounds__(256) void norm_x_k(const void* __restrict__ src,
                                                bf16* __restrict__ dst,
                                                const int* __restrict__ flag)
{
    const int qi = blockIdx.x * 256 + threadIdx.x;   // quad index, 4 elems each
    if (*flag) {
        ((uint2*)dst)[qi] = ((const uint2*)src)[qi];
    } else {
        float4 v = ((const float4*)src)[qi];
        Pack4 p;
        p.b[0] = (bf16)v.x; p.b[1] = (bf16)v.y;
        p.b[2] = (bf16)v.z; p.b[3] = (bf16)v.w;
        ((uint2*)dst)[qi] = p.q;
    }
}

// ---------------- bias normalization ----------------
__global__ __launch_bounds__(256) void norm_b_k(
    const void* __restrict__ b0, const void* __restrict__ b1,
    const void* __restrict__ b2, const void* __restrict__ b3,
    bf16* __restrict__ BN, const int* __restrict__ flag)
{
    const int mat = blockIdx.x;
    const void* src = (mat == 0) ? b0 : (mat == 1) ? b1 : (mat == 2) ? b2 : b3;
    bf16* dst = BN + mat * 1024;
    const int i = threadIdx.x * 4;
    if (*flag) {
        ((uint2*)(dst + i))[0] = *(const uint2*)((const bf16*)src + i);
    } else {
        const float* s = (const float*)src;
        Pack4 p;
        p.b[0] = (bf16)s[i + 0]; p.b[1] = (bf16)s[i + 1];
        p.b[2] = (bf16)s[i + 2]; p.b[3] = (bf16)s[i + 3];
        ((uint2*)(dst + i))[0] = p.q;
    }
}

// ---------- weight normalize + transpose: W[K][N] -> WT[N][K] (bf16) ----------
__global__ __launch_bounds__(256) void transpose_w(
    const void* __restrict__ W0, const void* __restrict__ W1,
    const void* __restrict__ W2, const void* __restrict__ W3,
    bf16* __restrict__ WT, const int* __restrict__ flag)
{
    __shared__ __align__(16) bf16 tile[64][65];
    const int mat = blockIdx.z;
    const void* W = (mat == 0) ? W0 : (mat == 1) ? W1 : (mat == 2) ? W2 : W3;
    bf16* O = WT + ((size_t)mat << 20);
    const int r0 = blockIdx.y * 64, c0 = blockIdx.x * 64;
    const int t = threadIdx.x;
    const int isb = *flag;
    #pragma unroll
    for (int i = 0; i < 16; ++i) {
        int idx = t + i * 256;
        int r = idx >> 6, c = idx & 63;
        size_t off = (size_t)(r0 + r) * D_ + c0 + c;
        tile[r][c] = isb ? ((const bf16*)W)[off] : (bf16)((const float*)W)[off];
    }
    __syncthreads();
    #pragma unroll
    for (int i = 0; i < 16; ++i) {
        int idx = t + i * 256;
        int rr = idx & 63, cc = idx >> 6;
        O[(size_t)(c0 + cc) * D_ + r0 + rr] = tile[rr][cc];
    }
}

// ---------------- shared 128x128 GEMM mainloop (m97 structure) ----------------
__device__ __forceinline__ void gemm_core(const bf16* __restrict__ A,
                                          const bf16* __restrict__ Bt,
                                          bf16* lA, bf16* lB,
                                          f32x4 acc[4][4], int m0, int n0)
{
    const int t = threadIdx.x;
    const int lane = t & 63;
    const int wave = t >> 6;
    const int wm = (wave >> 1) << 6;
    const int wn = (wave & 1) << 6;
    const int quad = lane >> 4;
    const int col = lane & 15;
    for (int k0 = 0; k0 < D_; k0 += 32) {
        #pragma unroll
        for (int i = 0; i < 2; ++i) {
            int slot = t + i * 256;
            int row = slot >> 2;
            int kc = (slot & 3) << 3;
            load16(A + (size_t)(m0 + row) * D_ + k0 + kc, lA + slot * 8);
            load16(Bt + (size_t)(n0 + row) * D_ + k0 + kc, lB + slot * 8);
        }
        __syncthreads();
        bf16x8 af[4], bfr[4];
        #pragma unroll
        for (int mi = 0; mi < 4; ++mi)
            af[mi] = *(const bf16x8*)(lA + (wm + mi * 16 + col) * 32 + quad * 8);
        #pragma unroll
        for (int ni = 0; ni < 4; ++ni)
            bfr[ni] = *(const bf16x8*)(lB + (wn + ni * 16 + col) * 32 + quad * 8);
        #pragma unroll
        for (int mi = 0; mi < 4; ++mi)
            #pragma unroll
            for (int ni = 0; ni < 4; ++ni)
                acc[mi][ni] = __builtin_amdgcn_mfma_f32_16x16x32_bf16(
                    af[mi], bfr[ni], acc[mi][ni], 0, 0, 0);
        __syncthreads();
    }
}

// ---------------- QKV projection ----------------
// mode 0: Q scaled by (1/8)*log2(e) -> [b][h][s][hd]; mode 1: K; mode 2: V^T
__global__ __launch_bounds__(256) void gemm_qkv_k(
    const bf16* __restrict__ X, const bf16* __restrict__ WT,
    const bf16* __restrict__ BN,
    bf16* __restrict__ Qo, bf16* __restrict__ Ko, bf16* __restrict__ Vo)
{
    __shared__ __align__(16) bf16 lA[128 * 32];
    __shared__ __align__(16) bf16 lB[128 * 32];
    const int mode = blockIdx.z;
    const bf16* Wsel = WT + ((size_t)mode << 20);
    const bf16* bias = BN + mode * 1024;
    f32x4 acc[4][4];
    const f32x4 z = {0.f, 0.f, 0.f, 0.f};
    #pragma unroll
    for (int i = 0; i < 4; ++i)
        #pragma unroll
        for (int j = 0; j < 4; ++j) acc[i][j] = z;
    const int m0 = blockIdx.x * 128, n0 = blockIdx.y * 128;
    gemm_core(X, Wsel, lA, lB, acc, m0, n0);
    const int t = threadIdx.x, lane = t & 63, wave = t >> 6;
    const int wm = (wave >> 1) << 6, wn = (wave & 1) << 6;
    const int quad = lane >> 4, col = lane & 15;
    // 0.125 * log2(e): softmax later uses raw exp2
    const float scale = (mode == 0) ? 0.18033688011112042f : 1.0f;
    #pragma unroll
    for (int mi = 0; mi < 4; ++mi) {
        int gm = m0 + wm + mi * 16 + quad * 4;
        int b = gm >> 11, srow = gm & 2047;
        #pragma unroll
        for (int ni = 0; ni < 4; ++ni) {
            int gn = n0 + wn + ni * 16 + col;
            float bb = (float)bias[gn];
            int h = gn >> 6, hd = gn & 63;
            #pragma unroll
            for (int r = 0; r < 4; ++r) {
                float v = (acc[mi][ni][r] + bb) * scale;
                if (mode == 2)
                    Vo[(((size_t)b * H_ + h) * HD_ + hd) * S_ + srow + r] = (bf16)v;
                else if (mode == 1)
                    Ko[(((size_t)b * H_ + h) * S_ + srow + r) * HD_ + hd] = (bf16)v;
                else
                    Qo[(((size_t)b * H_ + h) * S_ + srow + r) * HD_ + hd] = (bf16)v;
            }
        }
    }
}

// ---------------- flash attention (causal), S^T/O^T form ----------------
// grid: (S/128, B*H). block: 256 = 4 waves; wave w owns 32 q rows (2 n-tiles).
// K-tile = 64. S^T = K·Q^T (softmax reduction mostly in registers);
// O^T = V^T·P^T. All LDS fragment reads XOR-swizzled -> <=2-way conflicts.
__global__ __launch_bounds__(256) void attn_k(
    const bf16* __restrict__ Q, const bf16* __restrict__ K,
    const bf16* __restrict__ VT, bf16* __restrict__ Aout)
{
    __shared__ __align__(16) bf16 lK[64 * 64];      // [k][d], chunk^=(k&7)
    __shared__ __align__(16) bf16 lV[64 * 64];      // [d][k], chunk^=(d&7)
    __shared__ __align__(16) bf16 lPT[4][32 * 64];  // per-wave [q][k], chunk^=(q&7)
    const int bh = blockIdx.y;
    const int qc = (int)gridDim.x - 1 - (int)blockIdx.x; // big blocks first
    const int q0 = qc * 128;
    const bf16* Qp = Q + (size_t)bh * S_ * HD_;
    const bf16* Kp = K + (size_t)bh * S_ * HD_;
    const bf16* Vp = VT + (size_t)bh * HD_ * S_;
    const int t = threadIdx.x, lane = t & 63, w = t >> 6;
    const int quad = lane >> 4, col = lane & 15;
    const int wq0 = q0 + w * 32;

    // Q fragments (B-operand): B[n=q][k=d], n=col, k=quad*8+j
    bf16x8 qf[2][2];
    #pragma unroll
    for (int qt = 0; qt < 2; ++qt)
        #pragma unroll
        for (int cc = 0; cc < 2; ++cc)
            qf[qt][cc] = *(const bf16x8*)(Qp + (size_t)(wq0 + qt * 16 + col) * HD_
                                          + cc * 32 + quad * 8);
    f32x4 o[4][2];            // O^T acc: [d-tile][q-tile]
    float mst[2], lst[2];
    const f32x4 z = {0.f, 0.f, 0.f, 0.f};
    #pragma unroll
    for (int dt = 0; dt < 4; ++dt)
        #pragma unroll
        for (int qt = 0; qt < 2; ++qt) o[dt][qt] = z;
    mst[0] = mst[1] = NEG_SENT;
    lst[0] = lst[1] = 0.f;

    const int kend = q0 + 128;
    for (int k0 = 0; k0 < kend; k0 += 64) {
        // stage K[k0:+64][0:64] and V^T[0:64][k0:+64], xor-swizzled 8-chunks
        #pragma unroll
        for (int i = 0; i < 2; ++i) {
            int slot = t + i * 256;          // 0..511
            int rr = slot >> 3, ch = slot & 7;
            int sw = (ch ^ (rr & 7)) << 3;
            load16(Kp + (size_t)(k0 + rr) * HD_ + sw, lK + slot * 8);
            load16(Vp + (size_t)rr * S_ + k0 + sw, lV + slot * 8);
        }
        __syncthreads();
        if (k0 < wq0 + 32) {
            // S^T[mt=k][qt=q] = K·Q^T
            f32x4 st[4][2];
            #pragma unroll
            for (int mt = 0; mt < 4; ++mt)
                #pragma unroll
                for (int qt = 0; qt < 2; ++qt) st[mt][qt] = z;
            #pragma unroll
            for (int cc = 0; cc < 2; ++cc) {
                bf16x8 af[4];
                #pragma unroll
                for (int mt = 0; mt < 4; ++mt)
                    af[mt] = *(const bf16x8*)(lK + (mt * 16 + col) * 64
                              + (((cc * 4 + quad) ^ (col & 7)) << 3));
                #pragma unroll
                for (int mt = 0; mt < 4; ++mt)
                    #pragma unroll
                    for (int qt = 0; qt < 2; ++qt)
                        st[mt][qt] = __builtin_amdgcn_mfma_f32_16x16x32_bf16(
                            af[mt], qf[qt][cc], st[mt][qt], 0, 0, 0);
            }
            if (k0 + 64 > wq0) { // diagonal region: mask kg > qg
                #pragma unroll
                for (int mt = 0; mt < 4; ++mt)
                    #pragma unroll
                    for (int qt = 0; qt < 2; ++qt)
                        #pragma unroll
                        for (int r = 0; r < 4; ++r)
                            if (k0 + mt * 16 + quad * 4 + r > wq0 + qt * 16 + col)
                                st[mt][qt][r] = NEG_SENT;
            }
            // online softmax per q (= col), k-reduction in regs + 2 shuffles
            #pragma unroll
            for (int qt = 0; qt < 2; ++qt) {
                float tm = st[0][qt][0];
                #pragma unroll
                for (int mt = 0; mt < 4; ++mt)
                    #pragma unroll
                    for (int r = 0; r < 4; ++r)
                        tm = fmaxf(tm, st[mt][qt][r]);
                tm = fmaxf(tm, __shfl_xor(tm, 16));
                tm = fmaxf(tm, __shfl_xor(tm, 32));
                float mn = fmaxf(mst[qt], tm);
                float al = exp2f(mst[qt] - mn);
                mst[qt] = mn;
                float ssum = 0.f;
                #pragma unroll
                for (int mt = 0; mt < 4; ++mt)
                    #pragma unroll
                    for (int r = 0; r < 4; ++r) {
                        float p = exp2f(st[mt][qt][r] - mn);
                        st[mt][qt][r] = p;
                        ssum += p;
                    }
                ssum += __shfl_xor(ssum, 16);
                ssum += __shfl_xor(ssum, 32);
                lst[qt] = lst[qt] * al + ssum;
                #pragma unroll
                for (int dt = 0; dt < 4; ++dt) o[dt][qt] *= al;
                // P^T -> lPT[w] as [q][k], 4 consecutive k per lane, b64 writes
                #pragma unroll
                for (int mt = 0; mt < 4; ++mt) {
                    Pack4 pk;
                    #pragma unroll
                    for (int r = 0; r < 4; ++r) pk.b[r] = (bf16)st[mt][qt][r];
                    int qrow = qt * 16 + col;
                    int kch = mt * 2 + (quad >> 1);
                    *(uint2*)(&lPT[w][qrow * 64 + ((kch ^ (col & 7)) << 3)
                                      + ((quad & 1) << 2)]) = pk.q;
                }
            }
            // drain P writes before same-wave cross-lane reads
            asm volatile("s_waitcnt lgkmcnt(0)" ::: "memory");
            // O^T += V^T · P^T
            #pragma unroll
            for (int kk = 0; kk < 2; ++kk) {
                bf16x8 pf[2], vf[4];
                #pragma unroll
                for (int qt = 0; qt < 2; ++qt)
                    pf[qt] = *(const bf16x8*)(&lPT[w][(qt * 16 + col) * 64
                              + (((kk * 4 + quad) ^ (col & 7)) << 3)]);
                #pragma unroll
                for (int dt = 0; dt < 4; ++dt)
                    vf[dt] = *(const bf16x8*)(lV + (dt * 16 + col) * 64
                              + (((kk * 4 + quad) ^ (col & 7)) << 3));
                #pragma unroll
                for (int dt = 0; dt < 4; ++dt)
                    #pragma unroll
                    for (int qt = 0; qt < 2; ++qt)
                        o[dt][qt] = __builtin_amdgcn_mfma_f32_16x16x32_bf16(
                            vf[dt], pf[qt], o[dt][qt], 0, 0, 0);
            }
        }
        __syncthreads();
    }
    const int b = bh >> 4, h = bh & 15;
    #pragma unroll
    for (int qt = 0; qt < 2; ++qt) {
        float inv = 1.f / fmaxf(lst[qt], 1e-30f);
        int qg = wq0 + qt * 16 + col;
        #pragma unroll
        for (int dt = 0; dt < 4; ++dt) {
            Pack4 pk;
            #pragma unroll
            for (int r = 0; r < 4; ++r) pk.b[r] = (bf16)(o[dt][qt][r] * inv);
            *(uint2*)(Aout + ((size_t)b * S_ + qg) * D_ + h * HD_
                      + dt * 16 + quad * 4) = pk.q;
        }
    }
}

// ---------------- output projection (dtype-aware store) ----------------
__global__ __launch_bounds__(256) void gemm_out_k(
    const bf16* __restrict__ A, const bf16* __restrict__ WoT,
    const bf16* __restrict__ Bo, void* __restrict__ Out,
    const int* __restrict__ flag)
{
    __shared__ __align__(16) bf16 lA[128 * 32];
    __shared__ __align__(16) bf16 lB[128 * 32];
    f32x4 acc[4][4];
    const f32x4 z = {0.f, 0.f, 0.f, 0.f};
    #pragma unroll
    for (int i = 0; i < 4; ++i)
        #pragma unroll
        for (int j = 0; j < 4; ++j) acc[i][j] = z;
    const int m0 = blockIdx.x * 128, n0 = blockIdx.y * 128;
    gemm_core(A, WoT, lA, lB, acc, m0, n0);
    const int t = threadIdx.x, lane = t & 63, wave = t >> 6;
    const int wm = (wave >> 1) << 6, wn = (wave & 1) << 6;
    const int quad = lane >> 4, col = lane & 15;
    const int isb = *flag;
    #pragma unroll
    for (int mi = 0; mi < 4; ++mi) {
        int gm = m0 + wm + mi * 16 + quad * 4;
        #pragma unroll
        for (int ni = 0; ni < 4; ++ni) {
            int gn = n0 + wn + ni * 16 + col;
            float bb = (float)Bo[gn];
            #pragma unroll
            for (int r = 0; r < 4; ++r) {
                float v = acc[mi][ni][r] + bb;
                size_t off = (size_t)(gm + r) * D_ + gn;
                if (isb) ((bf16*)Out)[off] = (bf16)v;
                else     ((float*)Out)[off] = v;
            }
        }
    }
}

extern "C" void kernel_launch(void* const* d_in, const int* in_sizes, int n_in,
                              void* d_out, int out_size, void* d_ws, size_t ws_size,
                              hipStream_t stream)
{
    const void* x  = d_in[0];
    const void* wq = d_in[1];
    const void* bq = d_in[2];
    const void* wk = d_in[3];
    const void* bk = d_in[4];
    const void* wv = d_in[5];
    const void* bv = d_in[6];
    const void* wo = d_in[7];
    const void* bo = d_in[8];

    bf16* ws  = (bf16*)d_ws;
    bf16* XN  = ws + XN_OFF;                 // also reused as Ab
    bf16* WT  = ws + WT_OFF;
    bf16* BN  = ws + BN_OFF;
    int*  flag = (int*)((char*)d_ws + FLAG_BYTE);
    bf16* Qb  = ws + Q_OFF;
    bf16* Kb  = ws + K_OFF;
    bf16* VTb = ws + VT_OFF;
    bf16* Ab  = XN;

    hipLaunchKernelGGL(detect_k, dim3(1), dim3(256), 0, stream,
                       (const u16*)x, flag);
    hipLaunchKernelGGL(norm_x_k, dim3(8192), dim3(256), 0, stream,
                       x, XN, flag);
    hipLaunchKernelGGL(transpose_w, dim3(16, 16, 4), dim3(256), 0, stream,
                       wq, wk, wv, wo, WT, flag);
    hipLaunchKernelGGL(norm_b_k, dim3(4), dim3(256), 0, stream,
                       bq, bk, bv, bo, BN, flag);
    hipLaunchKernelGGL(gemm_qkv_k, dim3(64, 8, 3), dim3(256), 0, stream,
                       XN, WT, BN, Qb, Kb, VTb);
    hipLaunchKernelGGL(attn_k, dim3(16, 64), dim3(256), 0, stream,
                       Qb, Kb, VTb, Ab);
    hipLaunchKernelGGL(gemm_out_k, dim3(64, 8), dim3(256), 0, stream,
                       Ab, WT + ((size_t)3u << 20), BN + 3072, d_out, flag);
}